// Round 2
// baseline (534.161 us; speedup 1.0000x reference)
//
#include <hip/hip_runtime.h>
#include <hip/hip_bf16.h>

// GraphAwareTransformer: algebraically refactored.
//   logits[b,h,n] = <X[b,n,:], Qt[b,h,:]> + ebias[type[b,n],h]   (bk cancels in softmax)
//   ctx[b,h,:]    = sum_n attn[b,h,n] * X[b,n,:]
//   attn_out      = Wv_h ctx + bv ; then Wo, concat x, Wf, LN, relu
// Kernels: A (Qt), B (attention+ctx, reads the 256MB X once), C (final chain).
// All inputs fp32, output fp32 (per harness contract). ws holds bf16 Qt+ctx (32MB).

namespace {

constexpr float kScale = 0.17677669529663688f;  // 1/sqrt(32)

__device__ __forceinline__ float b2f(unsigned short u) {
  union { unsigned int i; float f; } v; v.i = ((unsigned int)u) << 16; return v.f;
}
__device__ __forceinline__ unsigned short f2bf(float f) {
  union { float fl; unsigned int i; } v; v.fl = f;
  unsigned int r = v.i + 0x7fffu + ((v.i >> 16) & 1u);  // RNE
  return (unsigned short)(r >> 16);
}

// ---------------- Kernel A: Qt[b,h,e] = kScale * sum_d (Wq x + bq)[h*32+d] * Wk[h*32+d, e]
__global__ __launch_bounds__(256) void qt_kernel(
    const float* __restrict__ cde, const float* __restrict__ Wq,
    const float* __restrict__ bq, const float* __restrict__ Wk,
    unsigned short* __restrict__ Qt) {
  __shared__ float xs[8 * 256];
  __shared__ float qs[8 * 256];
  const int t = threadIdx.x;
  const int b0 = blockIdx.x * 8;

  const float4* cde4 = (const float4*)(cde + (size_t)b0 * 256);
  float4* xs4 = (float4*)xs;
  xs4[t] = cde4[t];
  xs4[256 + t] = cde4[256 + t];
  __syncthreads();

  // Q step: thread t = output feature, 8 batch rows register-blocked.
  const float4* Wq4 = (const float4*)Wq;
  float4 acc[8];
#pragma unroll
  for (int r = 0; r < 8; ++r) acc[r] = make_float4(0.f, 0.f, 0.f, 0.f);
#pragma unroll 8
  for (int i = 0; i < 64; ++i) {
    float4 wv = Wq4[t * 64 + i];
#pragma unroll
    for (int r = 0; r < 8; ++r) {
      float4 x = xs4[r * 64 + i];
      acc[r].x = fmaf(wv.x, x.x, acc[r].x);
      acc[r].y = fmaf(wv.y, x.y, acc[r].y);
      acc[r].z = fmaf(wv.z, x.z, acc[r].z);
      acc[r].w = fmaf(wv.w, x.w, acc[r].w);
    }
  }
  const float bqv = bq[t];
#pragma unroll
  for (int r = 0; r < 8; ++r)
    qs[r * 256 + t] = bqv + (acc[r].x + acc[r].y) + (acc[r].z + acc[r].w);
  __syncthreads();

  // Qt step: thread t = e-column; Wk column reads are lane-coalesced.
  const float4* qs4 = (const float4*)qs;
  for (int h = 0; h < 8; ++h) {
    float a[8];
#pragma unroll
    for (int r = 0; r < 8; ++r) a[r] = 0.f;
#pragma unroll
    for (int d4 = 0; d4 < 8; ++d4) {
      const int rowb = h * 32 + d4 * 4;
      float w0 = Wk[(size_t)(rowb + 0) * 256 + t];
      float w1 = Wk[(size_t)(rowb + 1) * 256 + t];
      float w2 = Wk[(size_t)(rowb + 2) * 256 + t];
      float w3 = Wk[(size_t)(rowb + 3) * 256 + t];
#pragma unroll
      for (int r = 0; r < 8; ++r) {
        float4 q = qs4[r * 64 + h * 8 + d4];  // uniform LDS broadcast
        a[r] = fmaf(q.x, w0, a[r]);
        a[r] = fmaf(q.y, w1, a[r]);
        a[r] = fmaf(q.z, w2, a[r]);
        a[r] = fmaf(q.w, w3, a[r]);
      }
    }
#pragma unroll
    for (int r = 0; r < 8; ++r)
      Qt[((size_t)(b0 + r) * 8 + h) * 256 + t] = f2bf(a[r] * kScale);
  }
}

// ---------------- Kernel B: per batch row: logits -> softmax(+edge bias) -> ctx
// Block = 4 waves = one b. X[b] staged once in LDS as bf16 (stride 260 ushorts).
// Wave w owns heads {2w, 2w+1}. Phase1: lane = n. Ctx: lane = e-slice.
__global__ __launch_bounds__(256) void attn_ctx_kernel(
    const float* __restrict__ nemb, const int* __restrict__ ety,
    const float* __restrict__ ebias, const unsigned short* __restrict__ Qt,
    unsigned short* __restrict__ ctx) {
  __shared__ unsigned short Xs[64 * 260];
  const int t = threadIdx.x;
  const int b = blockIdx.x;
  const int lane = t & 63;

  // stage X[b] (64x256 f32 = 64KB) -> bf16 LDS, coalesced float4 loads
  const float4* X4 = (const float4*)(nemb + (size_t)b * 16384);
#pragma unroll
  for (int i = 0; i < 16; ++i) {
    int idx = i * 256 + t;            // float4 index in [0,4096)
    float4 v = X4[idx];
    ushort4 u;
    u.x = f2bf(v.x); u.y = f2bf(v.y); u.z = f2bf(v.z); u.w = f2bf(v.w);
    int row = idx >> 6, col = idx & 63;
    *(ushort4*)&Xs[row * 260 + col * 4] = u;
  }
  __syncthreads();

  const int w = __builtin_amdgcn_readfirstlane(t >> 6);
  const int h0 = 2 * w, h1 = 2 * w + 1;
  const ushort4* q0p = (const ushort4*)(Qt + ((size_t)b * 8 + h0) * 256);
  const ushort4* q1p = (const ushort4*)(Qt + ((size_t)b * 8 + h1) * 256);

  // Phase 1: lane = n; dot(X[n,:], Qt[h,:]) with wave-uniform Qt reads
  float4 A0 = make_float4(0.f, 0.f, 0.f, 0.f);
  float4 A1 = make_float4(0.f, 0.f, 0.f, 0.f);
#pragma unroll 4
  for (int e4 = 0; e4 < 64; ++e4) {
    ushort4 xu = *(const ushort4*)&Xs[lane * 260 + e4 * 4];
    ushort4 qu0 = q0p[e4];
    ushort4 qu1 = q1p[e4];
    float x0 = b2f(xu.x), x1 = b2f(xu.y), x2 = b2f(xu.z), x3 = b2f(xu.w);
    A0.x = fmaf(x0, b2f(qu0.x), A0.x);
    A0.y = fmaf(x1, b2f(qu0.y), A0.y);
    A0.z = fmaf(x2, b2f(qu0.z), A0.z);
    A0.w = fmaf(x3, b2f(qu0.w), A0.w);
    A1.x = fmaf(x0, b2f(qu1.x), A1.x);
    A1.y = fmaf(x1, b2f(qu1.y), A1.y);
    A1.z = fmaf(x2, b2f(qu1.z), A1.z);
    A1.w = fmaf(x3, b2f(qu1.w), A1.w);
  }
  float l0 = (A0.x + A0.y) + (A0.z + A0.w);
  float l1 = (A1.x + A1.y) + (A1.z + A1.w);
  const int e = ety[b * 64 + lane];
  l0 += ebias[e * 8 + h0];
  l1 += ebias[e * 8 + h1];

  // softmax over the 64 lanes (= neighbors)
  float m0 = l0, m1 = l1;
#pragma unroll
  for (int s = 32; s > 0; s >>= 1) {
    m0 = fmaxf(m0, __shfl_xor(m0, s, 64));
    m1 = fmaxf(m1, __shfl_xor(m1, s, 64));
  }
  float p0 = __expf(l0 - m0), p1 = __expf(l1 - m1);
  float s0 = p0, s1 = p1;
#pragma unroll
  for (int s = 32; s > 0; s >>= 1) {
    s0 += __shfl_xor(s0, s, 64);
    s1 += __shfl_xor(s1, s, 64);
  }
  const float at0 = p0 / s0, at1 = p1 / s1;

  // ctx: lane = e-slice of 4 floats; attn broadcast via shuffles
  float4 C0 = make_float4(0.f, 0.f, 0.f, 0.f);
  float4 C1 = make_float4(0.f, 0.f, 0.f, 0.f);
#pragma unroll 4
  for (int n = 0; n < 64; ++n) {
    ushort4 xu = *(const ushort4*)&Xs[n * 260 + lane * 4];
    float w0 = __shfl(at0, n, 64);
    float w1 = __shfl(at1, n, 64);
    float x0 = b2f(xu.x), x1 = b2f(xu.y), x2 = b2f(xu.z), x3 = b2f(xu.w);
    C0.x = fmaf(w0, x0, C0.x);
    C0.y = fmaf(w0, x1, C0.y);
    C0.z = fmaf(w0, x2, C0.z);
    C0.w = fmaf(w0, x3, C0.w);
    C1.x = fmaf(w1, x0, C1.x);
    C1.y = fmaf(w1, x1, C1.y);
    C1.z = fmaf(w1, x2, C1.z);
    C1.w = fmaf(w1, x3, C1.w);
  }
  ushort4 o0, o1;
  o0.x = f2bf(C0.x); o0.y = f2bf(C0.y); o0.z = f2bf(C0.z); o0.w = f2bf(C0.w);
  o1.x = f2bf(C1.x); o1.y = f2bf(C1.y); o1.z = f2bf(C1.z); o1.w = f2bf(C1.w);
  *(ushort4*)&ctx[((size_t)b * 8 + h0) * 256 + lane * 4] = o0;
  *(ushort4*)&ctx[((size_t)b * 8 + h1) * 256 + lane * 4] = o1;
}

// ---------------- Kernel C: attn_out = Wv_h ctx + bv; o = Wo ao + bo;
// y = Wf [o, x] + bf; LN; relu; fp32 out. 8 batch rows per block.
__global__ __launch_bounds__(256) void final_kernel(
    const unsigned short* __restrict__ ctx, const float* __restrict__ cde,
    const float* __restrict__ Wv, const float* __restrict__ bv,
    const float* __restrict__ Wo, const float* __restrict__ bo,
    const float* __restrict__ Wf, const float* __restrict__ bff,
    const float* __restrict__ gam, const float* __restrict__ bet,
    float* __restrict__ out) {
  __shared__ float ctxs[8 * 2048];  // 64 KB
  __shared__ float xsc[8 * 256];
  __shared__ float aos[8 * 256];
  __shared__ float osb[8 * 256];
  __shared__ float red[64];
  const int t = threadIdx.x;
  const int b0 = blockIdx.x * 8;

  const ushort4* c4 = (const ushort4*)(ctx + (size_t)b0 * 2048);
#pragma unroll
  for (int i = 0; i < 16; ++i) {
    ushort4 u = c4[i * 256 + t];
    float4 f = make_float4(b2f(u.x), b2f(u.y), b2f(u.z), b2f(u.w));
    *(float4*)&ctxs[(i * 256 + t) * 4] = f;
  }
  const float4* cde4 = (const float4*)(cde + (size_t)b0 * 256);
  ((float4*)xsc)[t] = cde4[t];
  ((float4*)xsc)[256 + t] = cde4[256 + t];
  __syncthreads();

  const int h = t >> 5;
  float4 A[8];

  // step 2: attn_out (thread t = feature h*32+d)
  const float4* Wv4 = (const float4*)Wv;
  const float4* ctxs4 = (const float4*)ctxs;
#pragma unroll
  for (int r = 0; r < 8; ++r) A[r] = make_float4(0.f, 0.f, 0.f, 0.f);
#pragma unroll 4
  for (int i = 0; i < 64; ++i) {
    float4 wv = Wv4[t * 64 + i];
#pragma unroll
    for (int r = 0; r < 8; ++r) {
      float4 c = ctxs4[r * 512 + h * 64 + i];
      A[r].x = fmaf(wv.x, c.x, A[r].x);
      A[r].y = fmaf(wv.y, c.y, A[r].y);
      A[r].z = fmaf(wv.z, c.z, A[r].z);
      A[r].w = fmaf(wv.w, c.w, A[r].w);
    }
  }
  const float bvv = bv[t];
#pragma unroll
  for (int r = 0; r < 8; ++r)
    aos[r * 256 + t] = bvv + (A[r].x + A[r].y) + (A[r].z + A[r].w);
  __syncthreads();

  // step 3: o = Wo ao + bo
  const float4* Wo4 = (const float4*)Wo;
  const float4* aos4 = (const float4*)aos;
#pragma unroll
  for (int r = 0; r < 8; ++r) A[r] = make_float4(0.f, 0.f, 0.f, 0.f);
#pragma unroll 4
  for (int i = 0; i < 64; ++i) {
    float4 wo = Wo4[t * 64 + i];
#pragma unroll
    for (int r = 0; r < 8; ++r) {
      float4 c = aos4[r * 64 + i];
      A[r].x = fmaf(wo.x, c.x, A[r].x);
      A[r].y = fmaf(wo.y, c.y, A[r].y);
      A[r].z = fmaf(wo.z, c.z, A[r].z);
      A[r].w = fmaf(wo.w, c.w, A[r].w);
    }
  }
  const float bov = bo[t];
#pragma unroll
  for (int r = 0; r < 8; ++r)
    osb[r * 256 + t] = bov + (A[r].x + A[r].y) + (A[r].z + A[r].w);
  __syncthreads();

  // step 4: y = Wf [o, x] + bf
  const float4* Wf4 = (const float4*)Wf;
  const float4* osb4 = (const float4*)osb;
  const float4* xsc4 = (const float4*)xsc;
#pragma unroll
  for (int r = 0; r < 8; ++r) A[r] = make_float4(0.f, 0.f, 0.f, 0.f);
#pragma unroll 4
  for (int i = 0; i < 64; ++i) {
    float4 wf = Wf4[t * 128 + i];
#pragma unroll
    for (int r = 0; r < 8; ++r) {
      float4 c = osb4[r * 64 + i];
      A[r].x = fmaf(wf.x, c.x, A[r].x);
      A[r].y = fmaf(wf.y, c.y, A[r].y);
      A[r].z = fmaf(wf.z, c.z, A[r].z);
      A[r].w = fmaf(wf.w, c.w, A[r].w);
    }
  }
#pragma unroll 4
  for (int i = 0; i < 64; ++i) {
    float4 wf = Wf4[t * 128 + 64 + i];
#pragma unroll
    for (int r = 0; r < 8; ++r) {
      float4 c = xsc4[r * 64 + i];
      A[r].x = fmaf(wf.x, c.x, A[r].x);
      A[r].y = fmaf(wf.y, c.y, A[r].y);
      A[r].z = fmaf(wf.z, c.z, A[r].z);
      A[r].w = fmaf(wf.w, c.w, A[r].w);
    }
  }
  const float bfv = bff[t];
  float y[8];
#pragma unroll
  for (int r = 0; r < 8; ++r)
    y[r] = bfv + (A[r].x + A[r].y) + (A[r].z + A[r].w);

  // LayerNorm over 256 features (256 threads)
  float sy[8], sy2[8];
#pragma unroll
  for (int r = 0; r < 8; ++r) { sy[r] = y[r]; sy2[r] = y[r] * y[r]; }
#pragma unroll
  for (int s = 32; s > 0; s >>= 1) {
#pragma unroll
    for (int r = 0; r < 8; ++r) {
      sy[r] += __shfl_xor(sy[r], s, 64);
      sy2[r] += __shfl_xor(sy2[r], s, 64);
    }
  }
  const int lane = t & 63, wid = t >> 6;
  if (lane == 0) {
#pragma unroll
    for (int r = 0; r < 8; ++r) {
      red[wid * 16 + r] = sy[r];
      red[wid * 16 + 8 + r] = sy2[r];
    }
  }
  __syncthreads();
  const float g = gam[t], be = bet[t];
#pragma unroll
  for (int r = 0; r < 8; ++r) {
    float S = red[r] + red[16 + r] + red[32 + r] + red[48 + r];
    float S2 = red[8 + r] + red[24 + r] + red[40 + r] + red[56 + r];
    float mu = S * (1.f / 256.f);
    float var = S2 * (1.f / 256.f) - mu * mu;
    float v = (y[r] - mu) * rsqrtf(var + 1e-5f) * g + be;
    out[(size_t)(b0 + r) * 256 + t] = fmaxf(v, 0.f);
  }
}

}  // namespace

extern "C" void kernel_launch(void* const* d_in, const int* in_sizes, int n_in,
                              void* d_out, int out_size, void* d_ws, size_t ws_size,
                              hipStream_t stream) {
  (void)in_sizes; (void)n_in; (void)out_size; (void)ws_size;
  const float* cde   = (const float*)d_in[0];
  const float* nemb  = (const float*)d_in[1];
  const int*   ety   = (const int*)d_in[2];
  const float* Wq    = (const float*)d_in[3];
  const float* bq    = (const float*)d_in[4];
  const float* Wk    = (const float*)d_in[5];
  // d_in[6] = bk: constant over n per (b,h) -> cancels in softmax, unused.
  const float* Wv    = (const float*)d_in[7];
  const float* bv    = (const float*)d_in[8];
  const float* Wo    = (const float*)d_in[9];
  const float* bo    = (const float*)d_in[10];
  const float* ebias = (const float*)d_in[11];
  const float* Wf    = (const float*)d_in[12];
  const float* bff   = (const float*)d_in[13];
  const float* gam   = (const float*)d_in[14];
  const float* bet   = (const float*)d_in[15];

  unsigned short* Qt  = (unsigned short*)d_ws;                 // 4096*8*256 bf16 = 16 MB
  unsigned short* ctx = Qt + (size_t)4096 * 2048;              // 16 MB more

  qt_kernel<<<512, 256, 0, stream>>>(cde, Wq, bq, Wk, Qt);
  attn_ctx_kernel<<<4096, 256, 0, stream>>>(nemb, ety, ebias, Qt, ctx);
  final_kernel<<<512, 256, 0, stream>>>(ctx, cde, Wv, bv, Wo, bo, Wf, bff,
                                        gam, bet, (float*)d_out);
}